// Round 10
// baseline (76.281 us; speedup 1.0000x reference)
//
#include <hip/hip_runtime.h>
#include <hip/hip_bf16.h>

#define NSEQ 2048
#define DD   64
#define HH   16
#define QT   128
#define KVB  64
#define NKV  (NSEQ / KVB)
#define NR   (NKV / 2)   /* rounds: each round covers one even + one odd tile */

typedef __attribute__((ext_vector_type(4)))  float f4;
typedef __attribute__((ext_vector_type(16))) float f32x16;
typedef __attribute__((ext_vector_type(8)))  short bf16x8;
typedef __attribute__((ext_vector_type(4)))  unsigned int u32x4;
typedef __attribute__((ext_vector_type(2)))  unsigned int u32x2;

#define QSCL  0.36067376022224085f  /* 2*scale*log2e = 0.25*log2(e); K stays raw */
#define LOG2E 1.4426950408889634f
#define NEGBIG (-1.0e30f)
#define THR   8.0f

/* K tile swizzle: slot = q ^ (row&7) — store 8-spread, read 8-spread */
#define SWZ(row, q)  (((row) << 6) + ((((q) ^ ((row) & 7))) << 3))
/* V tile swizzle: slot = q ^ ((d>>2)&7) ^ (d&3) — store 8-spread (dq fast), read 2-way */
#define SWZV(d, q)   (((d) << 6) + ((((q) ^ (((d) >> 2) & 7) ^ ((d) & 3))) << 3))

#if defined(__has_builtin)
#if __has_builtin(__builtin_amdgcn_exp2f)
#define EXP2F __builtin_amdgcn_exp2f
#endif
#if __has_builtin(__builtin_amdgcn_permlane32_swap)
#define HAVE_PLSWAP 1
#endif
#endif
#ifndef EXP2F
#define EXP2F exp2f
#endif

union bfu { u32x4 u; bf16x8 h; };

__device__ __forceinline__ unsigned cvtpk(float lo, float hi) {
    unsigned r;
    asm("v_cvt_pk_bf16_f32 %0, %1, %2" : "=v"(r) : "v"(lo), "v"(hi));
    return r;
}
template<int CTRL>
__device__ __forceinline__ float dppf(float x) {
    return __int_as_float(__builtin_amdgcn_update_dpp(
        0, __float_as_int(x), CTRL, 0xF, 0xF, true));
}
/* cross-half (lane ^ 32) reduce — direction-robust: combine BOTH outputs */
__device__ __forceinline__ float cross_max(float x) {
#ifdef HAVE_PLSWAP
    u32x2 r = __builtin_amdgcn_permlane32_swap(__float_as_uint(x), __float_as_uint(x),
                                               false, false);
    return fmaxf(__uint_as_float(r[0]), __uint_as_float(r[1]));
#else
    return fmaxf(x, __shfl_xor(x, 32));
#endif
}
__device__ __forceinline__ float cross_add(float x) {
#ifdef HAVE_PLSWAP
    u32x2 r = __builtin_amdgcn_permlane32_swap(__float_as_uint(x), __float_as_uint(x),
                                               false, false);
    return __uint_as_float(r[0]) + __uint_as_float(r[1]);
#else
    return x + __shfl_xor(x, 32);
#endif
}

__global__ __launch_bounds__(512, 2)
void attend_kernel(const float* __restrict__ qg, const float* __restrict__ kg,
                   const float* __restrict__ vg, const int* __restrict__ maskg,
                   float* __restrict__ outg)
{
    /* [parity][dbuf] — group g computes parity-g tiles */
    __shared__ __align__(16) unsigned short Ks[2][2][KVB * DD];   /* 32 KB */
    __shared__ __align__(16) unsigned short Vt[2][2][KVB * DD];   /* 32 KB */
    __shared__ __align__(16) float bias_s[2][2][KVB];             /*  2 KB */
    __shared__ __align__(16) float cmb_ml[2][4][64][2];           /*  4 KB */

    const int t    = threadIdx.x;
    const int w    = t >> 6;
    const int lane = t & 63;
    const int c5   = lane & 31;
    const int g2   = lane >> 5;
    const int g    = w >> 2;     /* KV parity group */
    const int rb   = w & 3;      /* 32-row block within Q tile */

    /* XCD-aware swizzle: 16 q-tiles of one head stay on one XCD */
    const int p     = blockIdx.x;
    const int bh    = (p & 7) * 4 + ((p >> 3) >> 4);
    const int qtile = (p >> 3) & 15;
    const int b     = bh >> 4;

    const size_t base = (size_t)bh * NSEQ * DD;
    const float* kp = kg + base;
    const float* vp = vg + base;
    const int*   mp = maskg + b * NSEQ;

    /* Q B-fragments, scaled by full 2*scale*log2e (K stays raw) */
    bfu qf[4];
    {
        const float* qp = qg + base + (size_t)(qtile*QT + rb*32 + c5) * DD;
        #pragma unroll
        for (int ck = 0; ck < 4; ++ck) {
            f4 a  = *(const f4*)(qp + ck*16 + g2*8);
            f4 bb = *(const f4*)(qp + ck*16 + g2*8 + 4);
            qf[ck].u = (u32x4){ cvtpk(a[0]*QSCL,  a[1]*QSCL),  cvtpk(a[2]*QSCL,  a[3]*QSCL),
                                cvtpk(bb[0]*QSCL, bb[1]*QSCL), cvtpk(bb[2]*QSCL, bb[3]*QSCL) };
        }
    }

    f32x16 acc0, acc1;
    #pragma unroll
    for (int r = 0; r < 16; ++r) { acc0[r] = 0.f; acc1[r] = 0.f; }
    float m_run = NEGBIG, l_run = 0.f;

    /* staging roles over 512 threads: [K-even | V-even | K-odd | V-odd] x 128 */
    const int  srole = t >> 7;
    const int  sid   = t & 127;
    const int  spar  = srole >> 1;     /* tile parity this thread stages */
    const bool isK   = !(srole & 1);
    const int  jK    = sid >> 1;       /* K row */
    const int  kq0   = (sid & 1) * 4;  /* K 16B-quad base (d-half) */
    const int  dq    = sid & 15;       /* V d-quad — fast-varying: coalesced global */
    const int  jq    = sid >> 4;       /* V col-octet */

    f4  st[8];
    int mr = 0;

    auto loadTile = [&](int rr) {      /* load tile (2*rr + spar) into regs */
        const int j0 = (2*rr + spar) * KVB;
        if (isK) {
            const float* src = kp + (size_t)(j0 + jK) * DD + kq0 * 8;
            #pragma unroll
            for (int i2 = 0; i2 < 8; ++i2) st[i2] = ((const f4*)src)[i2];
            mr = mp[j0 + jK];
        } else {
            #pragma unroll
            for (int i2 = 0; i2 < 8; ++i2)
                st[i2] = *(const f4*)(vp + (size_t)(j0 + jq*8 + i2) * DD + dq*4);
        }
    };

    auto stageTile = [&](int bsel) {
        if (isK) {
            float sq = 0.f;
            #pragma unroll
            for (int i2 = 0; i2 < 8; ++i2)
                sq += st[i2][0]*st[i2][0] + st[i2][1]*st[i2][1]
                    + st[i2][2]*st[i2][2] + st[i2][3]*st[i2][3];
            sq += dppf<0xB1>(sq);                   /* pair (xor1) reduce */
            if ((sid & 1) == 0) bias_s[spar][bsel][jK] = (mr > 0) ? NEGBIG : -sq * LOG2E;
            #pragma unroll
            for (int s2 = 0; s2 < 4; ++s2) {
                u32x4 kk = (u32x4){ cvtpk(st[2*s2][0],   st[2*s2][1]),
                                    cvtpk(st[2*s2][2],   st[2*s2][3]),
                                    cvtpk(st[2*s2+1][0], st[2*s2+1][1]),
                                    cvtpk(st[2*s2+1][2], st[2*s2+1][3]) };
                *(u32x4*)&Ks[spar][bsel][SWZ(jK, kq0 + s2)] = kk;
            }
        } else {
            #pragma unroll
            for (int cc = 0; cc < 4; ++cc) {
                int d = dq*4 + cc;
                u32x4 tv = (u32x4){ cvtpk(st[0][cc], st[1][cc]),
                                    cvtpk(st[2][cc], st[3][cc]),
                                    cvtpk(st[4][cc], st[5][cc]),
                                    cvtpk(st[6][cc], st[7][cc]) };
                *(u32x4*)&Vt[spar][bsel][SWZV(d, jq)] = tv;
            }
        }
    };

    loadTile(0);
    stageTile(0);
    loadTile(1);
    __syncthreads();

    for (int r = 0; r < NR; ++r) {
        const int cur = r & 1;
        if (r + 1 < NR) stageTile(cur ^ 1);
        if (r + 2 < NR) loadTile(r + 2);

        /* S^T = K_raw · Q_scaled;  bias (-|k|^2 log2e | mask) as C-init */
        f32x16 s01[2];
        #pragma unroll
        for (int jt = 0; jt < 2; ++jt) {
            f4 b4[4];
            #pragma unroll
            for (int q = 0; q < 4; ++q)
                b4[q] = *(const f4*)&bias_s[g][cur][32*jt + 8*q + 4*g2];
            f32x16 sc;
            #pragma unroll
            for (int rr = 0; rr < 16; ++rr) sc[rr] = b4[rr>>2][rr&3];
            __builtin_amdgcn_s_setprio(1);
            #pragma unroll
            for (int ck = 0; ck < 4; ++ck) {
                bfu kb;
                kb.u = *(const u32x4*)&Ks[g][cur][SWZ(32*jt + c5, 2*ck + g2)];
                sc = __builtin_amdgcn_mfma_f32_32x32x16_bf16(kb.h, qf[ck].h, sc, 0, 0, 0);
            }
            __builtin_amdgcn_s_setprio(0);
            s01[jt] = sc;
        }

        /* online softmax (query i = c5), cross-half reduce via permlane */
        float pmax;
        {
            float mm[8];
            #pragma unroll
            for (int i2 = 0; i2 < 8; ++i2)
                mm[i2] = fmaxf(fmaxf(s01[0][2*i2], s01[0][2*i2+1]),
                               fmaxf(s01[1][2*i2], s01[1][2*i2+1]));
            float ma = fmaxf(fmaxf(mm[0], mm[1]), fmaxf(mm[2], mm[3]));
            float mb = fmaxf(fmaxf(mm[4], mm[5]), fmaxf(mm[6], mm[7]));
            pmax = fmaxf(ma, mb);
        }
        pmax = cross_max(pmax);
        if (!__all(pmax <= m_run + THR)) {      /* defer-max (T13), monotone m */
            float mn = fmaxf(m_run, pmax);
            float corr = EXP2F(m_run - mn);
            m_run = mn;
            l_run *= corr;
            #pragma unroll
            for (int rr = 0; rr < 16; ++rr) { acc0[rr] *= corr; acc1[rr] *= corr; }
        }

        /* exp2 fused into bf16 pack (p never stored as f32 array) */
        unsigned Wp[16];
        float ls0 = 0.f, ls1 = 0.f;
        #pragma unroll
        for (int jt = 0; jt < 2; ++jt) {
            #pragma unroll
            for (int m = 0; m < 8; ++m) {
                float e0 = EXP2F(s01[jt][2*m]   - m_run);
                float e1 = EXP2F(s01[jt][2*m+1] - m_run);
                if (m & 1) ls1 += e0 + e1; else ls0 += e0 + e1;
                Wp[jt*8 + m] = cvtpk(e0, e1);
            }
        }
        l_run += cross_add(ls0 + ls1);

        /* build PV B-frags — R4-verified shfl_xor exchange */
        const bool hi = (g2 != 0);
        __builtin_amdgcn_s_setprio(1);
        #pragma unroll
        for (int ck = 0; ck < 4; ++ck) {
            const int bs = (ck >> 1) * 8 + 4 * (ck & 1);
            unsigned wA0 = Wp[bs], wA1 = Wp[bs+1], wB0 = Wp[bs+2], wB1 = Wp[bs+3];
            unsigned v  = hi ? wA0 : wB0;
            unsigned v2 = hi ? wA1 : wB1;
            unsigned x  = (unsigned)__shfl_xor((int)v, 32);
            unsigned x2 = (unsigned)__shfl_xor((int)v2, 32);
            bfu pb;
            pb.u = (u32x4){ hi ? x : wA0, hi ? x2 : wA1, hi ? wB0 : x, hi ? wB1 : x2 };
            bfu va0, va1;
            va0.u = *(const u32x4*)&Vt[g][cur][SWZV(     c5, 2*ck + g2)];
            va1.u = *(const u32x4*)&Vt[g][cur][SWZV(32 + c5, 2*ck + g2)];
            acc0 = __builtin_amdgcn_mfma_f32_32x32x16_bf16(va0.h, pb.h, acc0, 0, 0, 0);
            acc1 = __builtin_amdgcn_mfma_f32_32x32x16_bf16(va1.h, pb.h, acc1, 0, 0, 0);
        }
        __builtin_amdgcn_s_setprio(0);

        __syncthreads();
    }

    /* ---- combine the two KV-parity halves (waves w and w+4 share rows) ---- */
    cmb_ml[g][rb][lane][0] = m_run;
    cmb_ml[g][rb][lane][1] = l_run;
    __syncthreads();
    const float m_o = cmb_ml[g ^ 1][rb][lane][0];
    const float l_o = cmb_ml[g ^ 1][rb][lane][1];
    const float m_c  = fmaxf(m_run, m_o);
    const float corr = EXP2F(m_run - m_c);
    const float l_c  = l_run * corr + l_o * EXP2F(m_o - m_c);

    float* X = (float*)&Ks[0][0][0];   /* 32 KB scratch alias, [j][rb][lane] */
    if (g == 1) {
        #pragma unroll
        for (int q = 0; q < 16; ++q) X[(q      )*256 + rb*64 + lane] = acc0[q] * corr;
        #pragma unroll
        for (int q = 0; q < 16; ++q) X[(16 + q )*256 + rb*64 + lane] = acc1[q] * corr;
    }
    __syncthreads();
    if (g == 0) {
        const float inv = 1.0f / l_c;
        float* op = outg + base + (size_t)(qtile*QT + rb*32 + c5) * DD;
        #pragma unroll
        for (int dt = 0; dt < 2; ++dt) {
            const f32x16 A = dt ? acc1 : acc0;
            #pragma unroll
            for (int q = 0; q < 4; ++q) {
                f4 o;
                #pragma unroll
                for (int e = 0; e < 4; ++e) {
                    const int j = 4*q + e;
                    o[e] = (A[j] * corr + X[(dt*16 + j)*256 + rb*64 + lane]) * inv;
                }
                *(f4*)(op + 32*dt + 8*q + 4*g2) = o;
            }
        }
    }
}

extern "C" void kernel_launch(void* const* d_in, const int* in_sizes, int n_in,
                              void* d_out, int out_size, void* d_ws, size_t ws_size,
                              hipStream_t stream) {
    const float* q    = (const float*)d_in[0];
    const float* k    = (const float*)d_in[1];
    const float* v    = (const float*)d_in[2];
    const int*   mask = (const int*)d_in[3];
    float* out = (float*)d_out;
    attend_kernel<<<dim3(512), dim3(512), 0, stream>>>(q, k, v, mask, out);
}